// Round 1
// baseline (113.635 us; speedup 1.0000x reference)
//
#include <hip/hip_runtime.h>

#define NI 12   // input props
#define NR 6    // rules
#define NJ 2    // templates per rule
#define NL 2    // feature width
#define NV 4    // variables

// Derived-parameter layout in d_ws (floats):
//  [0  .. 59 ]  per (r,j) group g=r*NJ+j: A0, A1, W0n, W1n, Cn   (5 each)
//               n_i = A0*f0 + A1*f1 + W0n*f0^2 + W1n*f1^2 + Cn  (already * log2e, negated score)
//  [60 .. 107]  M[r][l][j][l'] = sum_v head_W[r,l,v]*body_W[r,j,v,l']   (((r*2+l)*2+j)*2+l')
//  [108.. 119]  C[r][l] = head_b[r,l] + sum_v head_W[r,l,v]*(body_b[r,0,v]+body_b[r,1,v])

__global__ void prep_kernel(const float* __restrict__ templates,
                            const float* __restrict__ gammas,
                            const float* __restrict__ body_W,
                            const float* __restrict__ body_b,
                            const float* __restrict__ head_W,
                            const float* __restrict__ head_b,
                            float* __restrict__ dp) {
    if (threadIdx.x != 0 || blockIdx.x != 0) return;
    const float LOG2E = 1.4426950408889634f;
    for (int r = 0; r < NR; ++r) {
        for (int j = 0; j < NJ; ++j) {
            int g = r * NJ + j;
            float g0 = fminf(fmaxf(gammas[g * NL + 0], 0.f), 1.f);
            float g1 = fminf(fmaxf(gammas[g * NL + 1], 0.f), 1.f);
            float w0 = 1.f - g0, w1 = 1.f - g1;
            float t0 = templates[g * NL + 0], t1 = templates[g * NL + 1];
            float wt0 = w0 * t0, wt1 = w1 * t1;
            float c0 = wt0 * t0 + wt1 * t1;
            dp[g * 5 + 0] = 2.f * LOG2E * wt0;
            dp[g * 5 + 1] = 2.f * LOG2E * wt1;
            dp[g * 5 + 2] = -LOG2E * w0;
            dp[g * 5 + 3] = -LOG2E * w1;
            dp[g * 5 + 4] = -LOG2E * c0;
        }
        for (int l = 0; l < NL; ++l) {
            for (int j = 0; j < NJ; ++j) {
                for (int lp = 0; lp < NL; ++lp) {
                    float acc = 0.f;
                    for (int v = 0; v < NV; ++v)
                        acc += head_W[(r * NL + l) * NV + v] *
                               body_W[((r * NJ + j) * NV + v) * NL + lp];
                    dp[60 + ((r * NL + l) * NJ + j) * NL + lp] = acc;
                }
            }
            float acc = head_b[r * NL + l];
            for (int v = 0; v < NV; ++v) {
                float bs = body_b[(r * NJ + 0) * NV + v] + body_b[(r * NJ + 1) * NV + v];
                acc += head_W[(r * NL + l) * NV + v] * bs;
            }
            dp[108 + r * NL + l] = acc;
        }
    }
}

__global__ __launch_bounds__(256) void
abstraction_main(const float* __restrict__ feat,
                 const float* __restrict__ dp,
                 float* __restrict__ out, int B) {
    int b = blockIdx.x * blockDim.x + threadIdx.x;
    if (b >= B) return;

    // Load the 24 features for this batch element (6 x float4, 16B/lane).
    const float4* fp = (const float4*)(feat + (size_t)b * (NI * NL));
    float f[NI * NL];
    #pragma unroll
    for (int k = 0; k < 6; ++k) {
        float4 v = fp[k];
        f[4 * k + 0] = v.x; f[4 * k + 1] = v.y;
        f[4 * k + 2] = v.z; f[4 * k + 3] = v.w;
    }
    float q[NI * NL];
    #pragma unroll
    for (int k = 0; k < NI * NL; ++k) q[k] = f[k] * f[k];

    float o[NR * NL];
    #pragma unroll
    for (int r = 0; r < NR; ++r) {
        float o0 = dp[108 + r * 2 + 0];
        float o1 = dp[108 + r * 2 + 1];
        #pragma unroll
        for (int j = 0; j < NJ; ++j) {
            const int g = r * NJ + j;
            const float A0 = dp[g * 5 + 0];
            const float A1 = dp[g * 5 + 1];
            const float W0 = dp[g * 5 + 2];
            const float W1 = dp[g * 5 + 3];
            const float Cn = dp[g * 5 + 4];
            float den = 0.f, a0 = 0.f, a1 = 0.f;
            #pragma unroll
            for (int i = 0; i < NI; ++i) {
                float x0 = f[2 * i], x1 = f[2 * i + 1];
                float n = fmaf(A0, x0, Cn);
                n = fmaf(A1, x1, n);
                n = fmaf(W0, q[2 * i], n);
                n = fmaf(W1, q[2 * i + 1], n);
                // exp2 of (-score * log2e) == exp(-score); args in [-1.8, 0] -> no max-sub needed
                float p = __builtin_amdgcn_exp2f(n);
                den += p;
                a0 = fmaf(p, x0, a0);
                a1 = fmaf(p, x1, a1);
            }
            float rinv = __builtin_amdgcn_rcpf(den);
            float s0 = a0 * rinv, s1 = a1 * rinv;
            const float m00 = dp[60 + ((r * 2 + 0) * 2 + j) * 2 + 0];
            const float m01 = dp[60 + ((r * 2 + 0) * 2 + j) * 2 + 1];
            const float m10 = dp[60 + ((r * 2 + 1) * 2 + j) * 2 + 0];
            const float m11 = dp[60 + ((r * 2 + 1) * 2 + j) * 2 + 1];
            o0 = fmaf(s0, m00, o0); o0 = fmaf(s1, m01, o0);
            o1 = fmaf(s0, m10, o1); o1 = fmaf(s1, m11, o1);
        }
        o[r * 2 + 0] = o0;
        o[r * 2 + 1] = o1;
    }

    float4* op = (float4*)(out + (size_t)b * (NR * NL));
    op[0] = make_float4(o[0], o[1], o[2], o[3]);
    op[1] = make_float4(o[4], o[5], o[6], o[7]);
    op[2] = make_float4(o[8], o[9], o[10], o[11]);
}

extern "C" void kernel_launch(void* const* d_in, const int* in_sizes, int n_in,
                              void* d_out, int out_size, void* d_ws, size_t ws_size,
                              hipStream_t stream) {
    (void)n_in; (void)out_size; (void)ws_size;
    const float* feat      = (const float*)d_in[0];
    const float* templates = (const float*)d_in[1];
    const float* gammas    = (const float*)d_in[2];
    const float* body_W    = (const float*)d_in[3];
    const float* body_b    = (const float*)d_in[4];
    const float* head_W    = (const float*)d_in[5];
    const float* head_b    = (const float*)d_in[6];
    float* out = (float*)d_out;
    float* dp  = (float*)d_ws;

    int B = in_sizes[0] / (NI * NL);

    hipLaunchKernelGGL(prep_kernel, dim3(1), dim3(64), 0, stream,
                       templates, gammas, body_W, body_b, head_W, head_b, dp);
    int blocks = (B + 255) / 256;
    hipLaunchKernelGGL(abstraction_main, dim3(blocks), dim3(256), 0, stream,
                       feat, dp, out, B);
}

// Round 2
// 109.075 us; speedup vs baseline: 1.0418x; 1.0418x over previous
//
#include <hip/hip_runtime.h>

#define NI 12   // input props
#define NR 6    // rules
#define NJ 2    // templates per rule
#define NL 2    // feature width
#define NV 4    // variables

typedef float v2f __attribute__((ext_vector_type(2)));

// Single fused kernel. Per-block, the first waves compute the 120 derived
// parameters into LDS (redundant across blocks, ~nothing), then every thread
// handles one batch element.
//
// Derived params:
//  sG[g*5+..] per (r,j) g=r*2+j: A0,A1,W0,W1,Cn with
//     n_i = x0*(W0*x0+A0) + x1*(W1*x1+A1) + Cn   (== -log2e * match_score)
//  sM[((r*2+l)*2+j)*2+lp] = sum_v head_W[r,l,v]*body_W[r,j,v,lp]
//  sC[r*2+l] = head_b[r,l] + sum_v head_W[r,l,v]*(body_b[r,0,v]+body_b[r,1,v])

__global__ __launch_bounds__(256) void
abstraction_fused(const float* __restrict__ feat,
                  const float* __restrict__ templates,
                  const float* __restrict__ gammas,
                  const float* __restrict__ body_W,
                  const float* __restrict__ body_b,
                  const float* __restrict__ head_W,
                  const float* __restrict__ head_b,
                  float* __restrict__ out, int B) {
    __shared__ float sG[NR * NJ * 5];
    __shared__ float sM[NR * NL * NJ * NL];
    __shared__ float sC[NR * NL];

    const int t = threadIdx.x;
    const float LOG2E = 1.4426950408889634f;

    if (t < NR * NJ) {
        // group params for g = t
        const int g = t;
        float g0 = fminf(fmaxf(gammas[g * NL + 0], 0.f), 1.f);
        float g1 = fminf(fmaxf(gammas[g * NL + 1], 0.f), 1.f);
        float w0 = 1.f - g0, w1 = 1.f - g1;
        float t0 = templates[g * NL + 0], t1 = templates[g * NL + 1];
        float wt0 = w0 * t0, wt1 = w1 * t1;
        float c0 = wt0 * t0 + wt1 * t1;
        sG[g * 5 + 0] = 2.f * LOG2E * wt0;
        sG[g * 5 + 1] = 2.f * LOG2E * wt1;
        sG[g * 5 + 2] = -LOG2E * w0;
        sG[g * 5 + 3] = -LOG2E * w1;
        sG[g * 5 + 4] = -LOG2E * c0;
    } else if (t >= 64 && t < 64 + NR * NL) {
        // head constants C[r][l]
        const int idx = t - 64;
        const int r = idx >> 1, l = idx & 1;
        float acc = head_b[r * NL + l];
        #pragma unroll
        for (int v = 0; v < NV; ++v) {
            float bs = body_b[(r * NJ + 0) * NV + v] + body_b[(r * NJ + 1) * NV + v];
            acc = fmaf(head_W[(r * NL + l) * NV + v], bs, acc);
        }
        sC[idx] = acc;
    } else if (t >= 128 && t < 128 + NR * NL * NJ * NL) {
        // fused matrix M[r][l][j][lp]
        const int idx = t - 128;
        const int lp = idx & 1, j = (idx >> 1) & 1, l = (idx >> 2) & 1, r = idx >> 3;
        float acc = 0.f;
        #pragma unroll
        for (int v = 0; v < NV; ++v)
            acc = fmaf(head_W[(r * NL + l) * NV + v],
                       body_W[((r * NJ + j) * NV + v) * NL + lp], acc);
        sM[idx] = acc;
    }
    __syncthreads();

    const int b = blockIdx.x * blockDim.x + t;
    if (b >= B) return;

    // 24 features: 6 x float4 (16B/lane, coalesced). Split by l-component.
    const float4* fp = (const float4*)(feat + (size_t)b * (NI * NL));
    float f0[NI], f1[NI];
    #pragma unroll
    for (int k = 0; k < 6; ++k) {
        float4 v = fp[k];
        f0[2 * k + 0] = v.x; f1[2 * k + 0] = v.y;
        f0[2 * k + 1] = v.z; f1[2 * k + 1] = v.w;
    }

    float o[NR * NL];
    #pragma unroll
    for (int r = 0; r < NR; ++r) {
        float o0 = sC[r * 2 + 0];
        float o1 = sC[r * 2 + 1];
        #pragma unroll
        for (int j = 0; j < NJ; ++j) {
            const int g = r * NJ + j;
            const v2f A0 = sG[g * 5 + 0];
            const v2f A1 = sG[g * 5 + 1];
            const v2f W0 = sG[g * 5 + 2];
            const v2f W1 = sG[g * 5 + 3];
            const v2f Cn = sG[g * 5 + 4];
            v2f den = 0.f, a0 = 0.f, a1 = 0.f;
            #pragma unroll
            for (int i = 0; i < NI; i += 2) {
                v2f X0 = { f0[i], f0[i + 1] };
                v2f X1 = { f1[i], f1[i + 1] };
                // n = X0*(W0*X0+A0) + X1*(W1*X1+A1) + Cn  (packed fp32)
                v2f n = __builtin_elementwise_fma(X0, __builtin_elementwise_fma(W0, X0, A0), Cn);
                n = __builtin_elementwise_fma(X1, __builtin_elementwise_fma(W1, X1, A1), n);
                // args in [-1.8, 0]: exp2 directly, no max-subtraction needed
                v2f p = { __builtin_amdgcn_exp2f(n.x), __builtin_amdgcn_exp2f(n.y) };
                den += p;
                a0 = __builtin_elementwise_fma(p, X0, a0);
                a1 = __builtin_elementwise_fma(p, X1, a1);
            }
            float d = den.x + den.y;
            float rinv = __builtin_amdgcn_rcpf(d);
            float s0 = (a0.x + a0.y) * rinv;
            float s1 = (a1.x + a1.y) * rinv;
            const float m00 = sM[((r * 2 + 0) * 2 + j) * 2 + 0];
            const float m01 = sM[((r * 2 + 0) * 2 + j) * 2 + 1];
            const float m10 = sM[((r * 2 + 1) * 2 + j) * 2 + 0];
            const float m11 = sM[((r * 2 + 1) * 2 + j) * 2 + 1];
            o0 = fmaf(s0, m00, o0); o0 = fmaf(s1, m01, o0);
            o1 = fmaf(s0, m10, o1); o1 = fmaf(s1, m11, o1);
        }
        o[r * 2 + 0] = o0;
        o[r * 2 + 1] = o1;
    }

    float4* op = (float4*)(out + (size_t)b * (NR * NL));
    op[0] = make_float4(o[0], o[1], o[2], o[3]);
    op[1] = make_float4(o[4], o[5], o[6], o[7]);
    op[2] = make_float4(o[8], o[9], o[10], o[11]);
}

extern "C" void kernel_launch(void* const* d_in, const int* in_sizes, int n_in,
                              void* d_out, int out_size, void* d_ws, size_t ws_size,
                              hipStream_t stream) {
    (void)n_in; (void)out_size; (void)d_ws; (void)ws_size;
    const float* feat      = (const float*)d_in[0];
    const float* templates = (const float*)d_in[1];
    const float* gammas    = (const float*)d_in[2];
    const float* body_W    = (const float*)d_in[3];
    const float* body_b    = (const float*)d_in[4];
    const float* head_W    = (const float*)d_in[5];
    const float* head_b    = (const float*)d_in[6];
    float* out = (float*)d_out;

    int B = in_sizes[0] / (NI * NL);
    int blocks = (B + 255) / 256;
    hipLaunchKernelGGL(abstraction_fused, dim3(blocks), dim3(256), 0, stream,
                       feat, templates, gammas, body_W, body_b, head_W, head_b,
                       out, B);
}